// Round 2
// baseline (2653.434 us; speedup 1.0000x reference)
//
#include <hip/hip_runtime.h>
#include <hip/hip_bf16.h>

#define NEG_SLOPE 0.01f
#define SCAN_B 1024

__device__ __forceinline__ void atomAddF(float* p, float v) {
    unsafeAtomicAdd(p, v);   // HW global_atomic_add_f32 (avoids CAS fallback)
}

// ---- histogram + weighted degree: count[row]++ ; deg[row] += attr -------
__global__ void hist_deg_kernel(const int* __restrict__ row, const float* __restrict__ attr,
                                int* __restrict__ count, float* __restrict__ deg, int E) {
    int i = blockIdx.x * blockDim.x + threadIdx.x;
    if (i < E) {
        int r = row[i];
        atomicAdd(&count[r], 1);
        atomAddF(&deg[r], attr[i]);
    }
}

// ---- dinv in-place: deg -> deg>0 ? rsqrt(deg) : 0 -----------------------
__global__ void dinv_kernel(float* deg, int N) {
    int i = blockIdx.x * blockDim.x + threadIdx.x;
    if (i < N) {
        float d = deg[i];
        deg[i] = d > 0.f ? rsqrtf(d) : 0.f;
    }
}

// ---- scan stage A: per-block sums of count ------------------------------
__global__ void blocksum_kernel(const int* __restrict__ count, int* __restrict__ bsum, int N) {
    __shared__ int red[SCAN_B];
    int i = blockIdx.x * SCAN_B + threadIdx.x;
    red[threadIdx.x] = (i < N) ? count[i] : 0;
    __syncthreads();
    for (int s = SCAN_B / 2; s > 0; s >>= 1) {
        if (threadIdx.x < s) red[threadIdx.x] += red[threadIdx.x + s];
        __syncthreads();
    }
    if (threadIdx.x == 0) bsum[blockIdx.x] = red[0];
}

// ---- scan stage B: exclusive scan of block sums (NB <= 128) -------------
__global__ void scan_bsums_kernel(const int* __restrict__ bsum, int* __restrict__ boff,
                                  int* __restrict__ rowptr, int NB, int N, int E) {
    __shared__ int red[128];
    int t = threadIdx.x;
    int v = (t < NB) ? bsum[t] : 0;
    red[t] = v;
    __syncthreads();
    for (int off = 1; off < 128; off <<= 1) {
        int x = (t >= off) ? red[t - off] : 0;
        __syncthreads();
        red[t] += x;
        __syncthreads();
    }
    if (t < NB) boff[t] = red[t] - v;   // exclusive
    if (t == 0) rowptr[N] = E;
}

// ---- scan stage C: intra-block exclusive scan + offset -> rowptr/cursor -
__global__ void scan_final_kernel(const int* __restrict__ count, const int* __restrict__ boff,
                                  int* __restrict__ rowptr, int* __restrict__ cursor, int N) {
    __shared__ int red[SCAN_B];
    int t = threadIdx.x;
    int i = blockIdx.x * SCAN_B + t;
    int v = (i < N) ? count[i] : 0;
    red[t] = v;
    __syncthreads();
    for (int off = 1; off < SCAN_B; off <<= 1) {
        int x = (t >= off) ? red[t - off] : 0;
        __syncthreads();
        red[t] += x;
        __syncthreads();
    }
    if (i < N) {
        int r = boff[blockIdx.x] + red[t] - v;  // exclusive prefix
        rowptr[i] = r;
        cursor[i] = r;
    }
}

// ---- scatter: sort edges by row; compute norm inline; accumulate cw -----
__global__ void scatter_kernel(const int* __restrict__ row, const int* __restrict__ col,
                               const float* __restrict__ attr, const float* __restrict__ dinv,
                               int* __restrict__ cursor, int2* __restrict__ spair,
                               float* __restrict__ cw, int E) {
    int e = blockIdx.x * blockDim.x + threadIdx.x;
    if (e >= E) return;
    int r = row[e], c = col[e];
    float nm = -dinv[r] * attr[e] * dinv[c];
    int pos = atomicAdd(&cursor[r], 1);
    spair[pos] = make_int2(c, __float_as_int(nm));
    atomAddF(&cw[c], nm);
}

// ---- h1 = leaky_relu(x @ w1 + b1), x:(N,20) w:(20,32) -------------------
__global__ void h1_kernel(const float* __restrict__ x, const float* __restrict__ w,
                          const float* __restrict__ b, float* __restrict__ h1, int N) {
    __shared__ float ws[20 * 32];
    __shared__ float bs[32];
    for (int t = threadIdx.x; t < 640; t += blockDim.x) ws[t] = w[t];
    if (threadIdx.x < 32) bs[threadIdx.x] = b[threadIdx.x];
    __syncthreads();
    int i = blockIdx.x * blockDim.x + threadIdx.x;
    if (i >= N) return;
    float xi[20];
#pragma unroll
    for (int k = 0; k < 20; k++) xi[k] = x[i * 20 + k];
    float acc[32];
#pragma unroll
    for (int j = 0; j < 32; j++) acc[j] = bs[j];
#pragma unroll
    for (int k = 0; k < 20; k++) {
        float a = xi[k];
#pragma unroll
        for (int j = 0; j < 32; j++) acc[j] += a * ws[k * 32 + j];
    }
#pragma unroll
    for (int j = 0; j < 32; j++) {
        float v = acc[j];
        h1[(long)i * 32 + j] = v > 0.f ? v : v * NEG_SLOPE;
    }
}

// ---- gather-propagate: p1[i] = sum_{e in CSR row i} norm*h1[col] --------
// 8 threads per node, each owning a float4 slice of the 32 features.
__global__ void gather_kernel(const int* __restrict__ rowptr, const int2* __restrict__ spair,
                              const float* __restrict__ h1, float* __restrict__ p1, int N) {
    long idx = (long)blockIdx.x * blockDim.x + threadIdx.x;
    int node = (int)(idx >> 3);
    int part = (int)(idx & 7);
    if (node >= N) return;
    int s0 = rowptr[node], s1 = rowptr[node + 1];
    const float4* h1v = (const float4*)h1;
    float4 acc = make_float4(0.f, 0.f, 0.f, 0.f);
    for (int e = s0; e < s1; e++) {
        int2 pr = spair[e];
        float nm = __int_as_float(pr.y);
        float4 v = h1v[(long)pr.x * 8 + part];
        acc.x += nm * v.x; acc.y += nm * v.y; acc.z += nm * v.z; acc.w += nm * v.w;
    }
    ((float4*)p1)[(long)node * 8 + part] = acc;
}

// ---- fused h2 + pooled sums: h2 = leaky(h1@w0 + p1@w1 + b2) in regs; ----
// s[j]    += sum_i h2[i][j]          (s1, for w3_0 path)
// s[64+j] += sum_i cw[i]*h2[i][j]    (s2, for w3_1 path; cw = col-norm sums)
__global__ void h2_fused_kernel(const float* __restrict__ h1, const float* __restrict__ p1,
                                const float* __restrict__ w0, const float* __restrict__ w1,
                                const float* __restrict__ b, const float* __restrict__ cw,
                                float* __restrict__ sbuf, int N) {
    __shared__ float w0s[32 * 64];
    __shared__ float w1s[32 * 64];
    __shared__ float bs[64];
    __shared__ float red[128];
    for (int t = threadIdx.x; t < 2048; t += blockDim.x) { w0s[t] = w0[t]; w1s[t] = w1[t]; }
    if (threadIdx.x < 64) bs[threadIdx.x] = b[threadIdx.x];
    for (int t = threadIdx.x; t < 128; t += blockDim.x) red[t] = 0.f;
    __syncthreads();
    int i = blockIdx.x * blockDim.x + threadIdx.x;
    bool active = i < N;
    float acc[64];
    if (active) {
#pragma unroll
        for (int j = 0; j < 64; j++) acc[j] = bs[j];
        const float4* h1v = (const float4*)(h1 + (long)i * 32);
        const float4* p1v = (const float4*)(p1 + (long)i * 32);
#pragma unroll
        for (int k4 = 0; k4 < 8; k4++) {
            float4 a = h1v[k4];
            float4 p = p1v[k4];
            float av[4] = {a.x, a.y, a.z, a.w};
            float pv[4] = {p.x, p.y, p.z, p.w};
#pragma unroll
            for (int s = 0; s < 4; s++) {
                int k = k4 * 4 + s;
#pragma unroll
                for (int j = 0; j < 64; j++)
                    acc[j] += av[s] * w0s[k * 64 + j] + pv[s] * w1s[k * 64 + j];
            }
        }
        float w = cw[i];
#pragma unroll
        for (int j = 0; j < 64; j++) {
            float v = acc[j];
            v = v > 0.f ? v : v * NEG_SLOPE;
            atomicAdd(&red[j], v);
            atomicAdd(&red[64 + j], w * v);
        }
    }
    __syncthreads();
    for (int t = threadIdx.x; t < 128; t += blockDim.x) atomAddF(&sbuf[t], red[t]);
}

// ---- pooled = (s1/N)@w30 + (s2/N)@w31 + b3; out = log_softmax -----------
__global__ void final_kernel(const float* __restrict__ sbuf,
                             const float* __restrict__ w30, const float* __restrict__ w31,
                             const float* __restrict__ b3, float* __restrict__ out, float invN) {
    if (threadIdx.x != 0 || blockIdx.x != 0) return;
    const float* s1 = sbuf;
    const float* s2 = sbuf + 64;
    float p[2];
    for (int c = 0; c < 2; c++) {
        float a = 0.f;
        for (int k = 0; k < 64; k++) a += s1[k] * w30[k * 2 + c] + s2[k] * w31[k * 2 + c];
        p[c] = a * invN + b3[c];
    }
    float m = fmaxf(p[0], p[1]);
    float lse = m + logf(expf(p[0] - m) + expf(p[1] - m));
    out[0] = p[0] - lse;
    out[1] = p[1] - lse;
}

extern "C" void kernel_launch(void* const* d_in, const int* in_sizes, int n_in,
                              void* d_out, int out_size, void* d_ws, size_t ws_size,
                              hipStream_t stream) {
    const float* x    = (const float*)d_in[0];
    const int*   ei   = (const int*)d_in[1];
    const float* attr = (const float*)d_in[2];
    const float* w1_0 = (const float*)d_in[3];
    const float* b1   = (const float*)d_in[4];
    const float* w2_0 = (const float*)d_in[5];
    const float* w2_1 = (const float*)d_in[6];
    const float* b2   = (const float*)d_in[7];
    const float* w3_0 = (const float*)d_in[8];
    const float* w3_1 = (const float*)d_in[9];
    const float* b3   = (const float*)d_in[10];

    const int N = in_sizes[0] / 20;   // 100000
    const int E = in_sizes[2];        // 3200000
    const int* row = ei;
    const int* col = ei + E;

    // workspace layout (words); N is a multiple of 4 here
    float* ws = (float*)d_ws;
    float* deg    = ws;                       // N  (becomes dinv)
    int*   count  = (int*)(ws + N);           // N
    int*   rowptr = (int*)(ws + 2L * N);      // N+1 (alloc N+4)
    int*   cursor = (int*)(ws + 3L * N + 4);  // N
    float* cw     = ws + 4L * N + 4;          // N
    int*   bsum   = (int*)(ws + 5L * N + 4);  // 128
    int*   boff   = (int*)(ws + 5L * N + 132);// 128
    float* sbuf   = ws + 5L * N + 260;        // 128
    int2*  spair  = (int2*)(ws + 5L * N + 388); // E int2 = 2E words (offset even+16B ok)
    float* h1     = ws + 5L * N + 388 + 2L * E; // 32N
    float* p1     = h1 + 32L * N;               // 32N

    // zero accumulated regions (ws is poisoned before every launch)
    hipMemsetAsync(deg, 0, (size_t)N * 4, stream);
    hipMemsetAsync(count, 0, (size_t)N * 4, stream);
    hipMemsetAsync(cw, 0, (size_t)N * 4, stream);
    hipMemsetAsync(sbuf, 0, 128 * 4, stream);

    const int B = 256;
    const int NB = (N + SCAN_B - 1) / SCAN_B;   // 98 <= 128

    hist_deg_kernel<<<(E + B - 1) / B, B, 0, stream>>>(row, attr, count, deg, E);
    dinv_kernel<<<(N + B - 1) / B, B, 0, stream>>>(deg, N);
    blocksum_kernel<<<NB, SCAN_B, 0, stream>>>(count, bsum, N);
    scan_bsums_kernel<<<1, 128, 0, stream>>>(bsum, boff, rowptr, NB, N, E);
    scan_final_kernel<<<NB, SCAN_B, 0, stream>>>(count, boff, rowptr, cursor, N);
    scatter_kernel<<<(E + B - 1) / B, B, 0, stream>>>(row, col, attr, deg, cursor, spair, cw, E);
    h1_kernel<<<(N + B - 1) / B, B, 0, stream>>>(x, w1_0, b1, h1, N);
    {
        long t = (long)N * 8;
        gather_kernel<<<(int)((t + B - 1) / B), B, 0, stream>>>(rowptr, spair, h1, p1, N);
    }
    h2_fused_kernel<<<(N + B - 1) / B, B, 0, stream>>>(h1, p1, w2_0, w2_1, b2, cw, sbuf, N);
    final_kernel<<<1, 64, 0, stream>>>(sbuf, w3_0, w3_1, b3, (float*)d_out, 1.0f / (float)N);
}

// Round 3
// 903.675 us; speedup vs baseline: 2.9363x; 2.9363x over previous
//
#include <hip/hip_runtime.h>
#include <hip/hip_bf16.h>

#define NEG_SLOPE 0.01f
#define SCAN_B 1024

__device__ __forceinline__ void atomAddF(float* p, float v) {
    unsafeAtomicAdd(p, v);   // HW global_atomic_add_f32 (avoids CAS fallback)
}

// ---- histogram + weighted degree: count[row]++ ; deg[row] += attr -------
__global__ void hist_deg_kernel(const int* __restrict__ row, const float* __restrict__ attr,
                                int* __restrict__ count, float* __restrict__ deg, int E) {
    int i = blockIdx.x * blockDim.x + threadIdx.x;
    if (i < E) {
        int r = row[i];
        atomicAdd(&count[r], 1);
        atomAddF(&deg[r], attr[i]);
    }
}

// ---- dinv in-place: deg -> deg>0 ? rsqrt(deg) : 0 -----------------------
__global__ void dinv_kernel(float* deg, int N) {
    int i = blockIdx.x * blockDim.x + threadIdx.x;
    if (i < N) {
        float d = deg[i];
        deg[i] = d > 0.f ? rsqrtf(d) : 0.f;
    }
}

// ---- scan stage A: per-block sums of count ------------------------------
__global__ void blocksum_kernel(const int* __restrict__ count, int* __restrict__ bsum, int N) {
    __shared__ int red[SCAN_B];
    int i = blockIdx.x * SCAN_B + threadIdx.x;
    red[threadIdx.x] = (i < N) ? count[i] : 0;
    __syncthreads();
    for (int s = SCAN_B / 2; s > 0; s >>= 1) {
        if (threadIdx.x < s) red[threadIdx.x] += red[threadIdx.x + s];
        __syncthreads();
    }
    if (threadIdx.x == 0) bsum[blockIdx.x] = red[0];
}

// ---- scan stage B: exclusive scan of block sums (NB <= 128) -------------
__global__ void scan_bsums_kernel(const int* __restrict__ bsum, int* __restrict__ boff,
                                  int* __restrict__ rowptr, int NB, int N, int E) {
    __shared__ int red[128];
    int t = threadIdx.x;
    int v = (t < NB) ? bsum[t] : 0;
    red[t] = v;
    __syncthreads();
    for (int off = 1; off < 128; off <<= 1) {
        int x = (t >= off) ? red[t - off] : 0;
        __syncthreads();
        red[t] += x;
        __syncthreads();
    }
    if (t < NB) boff[t] = red[t] - v;   // exclusive
    if (t == 0) rowptr[N] = E;
}

// ---- scan stage C: intra-block exclusive scan + offset -> rowptr/cursor -
__global__ void scan_final_kernel(const int* __restrict__ count, const int* __restrict__ boff,
                                  int* __restrict__ rowptr, int* __restrict__ cursor, int N) {
    __shared__ int red[SCAN_B];
    int t = threadIdx.x;
    int i = blockIdx.x * SCAN_B + t;
    int v = (i < N) ? count[i] : 0;
    red[t] = v;
    __syncthreads();
    for (int off = 1; off < SCAN_B; off <<= 1) {
        int x = (t >= off) ? red[t - off] : 0;
        __syncthreads();
        red[t] += x;
        __syncthreads();
    }
    if (i < N) {
        int r = boff[blockIdx.x] + red[t] - v;  // exclusive prefix
        rowptr[i] = r;
        cursor[i] = r;
    }
}

// ---- scatter: sort edges by row; compute norm inline; accumulate cw -----
__global__ void scatter_kernel(const int* __restrict__ row, const int* __restrict__ col,
                               const float* __restrict__ attr, const float* __restrict__ dinv,
                               int* __restrict__ cursor, int2* __restrict__ spair,
                               float* __restrict__ cw, int E) {
    int e = blockIdx.x * blockDim.x + threadIdx.x;
    if (e >= E) return;
    int r = row[e], c = col[e];
    float nm = -dinv[r] * attr[e] * dinv[c];
    int pos = atomicAdd(&cursor[r], 1);
    spair[pos] = make_int2(c, __float_as_int(nm));
    atomAddF(&cw[c], nm);
}

// ---- h1 = leaky_relu(x @ w1 + b1), x:(N,20) w:(20,32) -------------------
__global__ void h1_kernel(const float* __restrict__ x, const float* __restrict__ w,
                          const float* __restrict__ b, float* __restrict__ h1, int N) {
    __shared__ float ws[20 * 32];
    __shared__ float bs[32];
    for (int t = threadIdx.x; t < 640; t += blockDim.x) ws[t] = w[t];
    if (threadIdx.x < 32) bs[threadIdx.x] = b[threadIdx.x];
    __syncthreads();
    int i = blockIdx.x * blockDim.x + threadIdx.x;
    if (i >= N) return;
    float xi[20];
#pragma unroll
    for (int k = 0; k < 20; k++) xi[k] = x[i * 20 + k];
    float acc[32];
#pragma unroll
    for (int j = 0; j < 32; j++) acc[j] = bs[j];
#pragma unroll
    for (int k = 0; k < 20; k++) {
        float a = xi[k];
#pragma unroll
        for (int j = 0; j < 32; j++) acc[j] += a * ws[k * 32 + j];
    }
#pragma unroll
    for (int j = 0; j < 32; j++) {
        float v = acc[j];
        h1[(long)i * 32 + j] = v > 0.f ? v : v * NEG_SLOPE;
    }
}

// ---- gather-propagate: p1[i] = sum_{e in CSR row i} norm*h1[col] --------
// 8 threads per node, each owning a float4 slice of the 32 features.
__global__ void gather_kernel(const int* __restrict__ rowptr, const int2* __restrict__ spair,
                              const float* __restrict__ h1, float* __restrict__ p1, int N) {
    long idx = (long)blockIdx.x * blockDim.x + threadIdx.x;
    int node = (int)(idx >> 3);
    int part = (int)(idx & 7);
    if (node >= N) return;
    int s0 = rowptr[node], s1 = rowptr[node + 1];
    const float4* h1v = (const float4*)h1;
    float4 acc = make_float4(0.f, 0.f, 0.f, 0.f);
    for (int e = s0; e < s1; e++) {
        int2 pr = spair[e];
        float nm = __int_as_float(pr.y);
        float4 v = h1v[(long)pr.x * 8 + part];
        acc.x += nm * v.x; acc.y += nm * v.y; acc.z += nm * v.z; acc.w += nm * v.w;
    }
    ((float4*)p1)[(long)node * 8 + part] = acc;
}

// ---- h2 = leaky_relu(h1 @ w2_0 + p1 @ w2_1 + b2), 32 -> 64 --------------
__global__ void __launch_bounds__(256, 1)
h2_kernel(const float* __restrict__ h1, const float* __restrict__ p1,
          const float* __restrict__ w0, const float* __restrict__ w1,
          const float* __restrict__ b, float* __restrict__ h2, int N) {
    __shared__ float w0s[32 * 64];
    __shared__ float w1s[32 * 64];
    __shared__ float bs[64];
    for (int t = threadIdx.x; t < 2048; t += blockDim.x) { w0s[t] = w0[t]; w1s[t] = w1[t]; }
    if (threadIdx.x < 64) bs[threadIdx.x] = b[threadIdx.x];
    __syncthreads();
    int i = blockIdx.x * blockDim.x + threadIdx.x;
    if (i >= N) return;
    float acc[64];
#pragma unroll
    for (int j = 0; j < 64; j++) acc[j] = bs[j];
    const float4* h1v = (const float4*)(h1 + (long)i * 32);
    const float4* p1v = (const float4*)(p1 + (long)i * 32);
#pragma unroll
    for (int k4 = 0; k4 < 8; k4++) {
        float4 a = h1v[k4];
        float4 p = p1v[k4];
        float av[4] = {a.x, a.y, a.z, a.w};
        float pv[4] = {p.x, p.y, p.z, p.w};
#pragma unroll
        for (int s = 0; s < 4; s++) {
            int k = k4 * 4 + s;
#pragma unroll
            for (int j = 0; j < 64; j++)
                acc[j] += av[s] * w0s[k * 64 + j] + pv[s] * w1s[k * 64 + j];
        }
    }
#pragma unroll
    for (int j = 0; j < 64; j++) {
        float v = acc[j];
        acc[j] = v > 0.f ? v : v * NEG_SLOPE;
    }
    float4* out = (float4*)(h2 + (long)i * 64);
#pragma unroll
    for (int j = 0; j < 16; j++)
        out[j] = make_float4(acc[4 * j], acc[4 * j + 1], acc[4 * j + 2], acc[4 * j + 3]);
}

// ---- fused pooled sums over h2: --------------------------------------
// sbuf[j]    += sum_i h2[i][j]           (plain mean path, w3_0)
// sbuf[64+j] += sum_i cw[i] * h2[i][j]   (propagated mean path, w3_1)
// Feature id == idx & 63; wave-aligned so cw[node] is a broadcast load.
__global__ void sum2_kernel(const float* __restrict__ h2, const float* __restrict__ cw,
                            float* __restrict__ sbuf, long total) {
    long tid = (long)blockIdx.x * blockDim.x + threadIdx.x;
    long stride = (long)gridDim.x * blockDim.x;   // multiple of 64
    float a1 = 0.f, a2 = 0.f;
    for (long idx = tid; idx < total; idx += stride) {
        float v = h2[idx];
        a1 += v;
        a2 += cw[idx >> 6] * v;
    }
    __shared__ float red1[256];
    __shared__ float red2[256];
    red1[threadIdx.x] = a1;
    red2[threadIdx.x] = a2;
    __syncthreads();
    if (threadIdx.x < 64) {
        float s1 = red1[threadIdx.x] + red1[threadIdx.x + 64] + red1[threadIdx.x + 128] + red1[threadIdx.x + 192];
        float s2 = red2[threadIdx.x] + red2[threadIdx.x + 64] + red2[threadIdx.x + 128] + red2[threadIdx.x + 192];
        atomAddF(&sbuf[threadIdx.x], s1);        // feature id == threadIdx.x
        atomAddF(&sbuf[64 + threadIdx.x], s2);
    }
}

// ---- pooled = (s1/N)@w30 + (s2/N)@w31 + b3; out = log_softmax -----------
__global__ void final_kernel(const float* __restrict__ sbuf,
                             const float* __restrict__ w30, const float* __restrict__ w31,
                             const float* __restrict__ b3, float* __restrict__ out, float invN) {
    if (threadIdx.x != 0 || blockIdx.x != 0) return;
    const float* s1 = sbuf;
    const float* s2 = sbuf + 64;
    float p[2];
    for (int c = 0; c < 2; c++) {
        float a = 0.f;
        for (int k = 0; k < 64; k++) a += s1[k] * w30[k * 2 + c] + s2[k] * w31[k * 2 + c];
        p[c] = a * invN + b3[c];
    }
    float m = fmaxf(p[0], p[1]);
    float lse = m + logf(expf(p[0] - m) + expf(p[1] - m));
    out[0] = p[0] - lse;
    out[1] = p[1] - lse;
}

extern "C" void kernel_launch(void* const* d_in, const int* in_sizes, int n_in,
                              void* d_out, int out_size, void* d_ws, size_t ws_size,
                              hipStream_t stream) {
    const float* x    = (const float*)d_in[0];
    const int*   ei   = (const int*)d_in[1];
    const float* attr = (const float*)d_in[2];
    const float* w1_0 = (const float*)d_in[3];
    const float* b1   = (const float*)d_in[4];
    const float* w2_0 = (const float*)d_in[5];
    const float* w2_1 = (const float*)d_in[6];
    const float* b2   = (const float*)d_in[7];
    const float* w3_0 = (const float*)d_in[8];
    const float* w3_1 = (const float*)d_in[9];
    const float* b3   = (const float*)d_in[10];

    const int N = in_sizes[0] / 20;   // 100000
    const int E = in_sizes[2];        // 3200000
    const int* row = ei;
    const int* col = ei + E;

    // workspace layout (words); N is a multiple of 4 here
    float* ws = (float*)d_ws;
    float* deg    = ws;                       // N  (becomes dinv)
    int*   count  = (int*)(ws + N);           // N
    int*   rowptr = (int*)(ws + 2L * N);      // N+1 (alloc N+4)
    int*   cursor = (int*)(ws + 3L * N + 4);  // N
    float* cw     = ws + 4L * N + 4;          // N
    int*   bsum   = (int*)(ws + 5L * N + 4);  // 128
    int*   boff   = (int*)(ws + 5L * N + 132);// 128
    float* sbuf   = ws + 5L * N + 260;        // 128
    int2*  spair  = (int2*)(ws + 5L * N + 388); // E int2 = 2E words
    float* h1     = ws + 5L * N + 388 + 2L * E; // 32N
    float* p1     = h1 + 32L * N;               // 32N
    // h2 overlays spair: spair is dead after gather_kernel; 64N == 2E words.
    float* h2     = (float*)spair;

    // zero accumulated regions (ws is poisoned before every launch)
    hipMemsetAsync(deg, 0, (size_t)N * 4, stream);
    hipMemsetAsync(count, 0, (size_t)N * 4, stream);
    hipMemsetAsync(cw, 0, (size_t)N * 4, stream);
    hipMemsetAsync(sbuf, 0, 128 * 4, stream);

    const int B = 256;
    const int NB = (N + SCAN_B - 1) / SCAN_B;   // 98 <= 128

    hist_deg_kernel<<<(E + B - 1) / B, B, 0, stream>>>(row, attr, count, deg, E);
    dinv_kernel<<<(N + B - 1) / B, B, 0, stream>>>(deg, N);
    blocksum_kernel<<<NB, SCAN_B, 0, stream>>>(count, bsum, N);
    scan_bsums_kernel<<<1, 128, 0, stream>>>(bsum, boff, rowptr, NB, N, E);
    scan_final_kernel<<<NB, SCAN_B, 0, stream>>>(count, boff, rowptr, cursor, N);
    scatter_kernel<<<(E + B - 1) / B, B, 0, stream>>>(row, col, attr, deg, cursor, spair, cw, E);
    h1_kernel<<<(N + B - 1) / B, B, 0, stream>>>(x, w1_0, b1, h1, N);
    {
        long t = (long)N * 8;
        gather_kernel<<<(int)((t + B - 1) / B), B, 0, stream>>>(rowptr, spair, h1, p1, N);
    }
    h2_kernel<<<(N + B - 1) / B, B, 0, stream>>>(h1, p1, w2_0, w2_1, b2, h2, N);
    sum2_kernel<<<256, B, 0, stream>>>(h2, cw, sbuf, (long)N * 64);
    final_kernel<<<1, 64, 0, stream>>>(sbuf, w3_0, w3_1, b3, (float*)d_out, 1.0f / (float)N);
}